// Round 6
// baseline (1397.913 us; speedup 1.0000x reference)
//
#include <hip/hip_runtime.h>

// NLIF fused step, two-pass mixed precision.
//   FULL tier (ws >= ~105MB): prep kernel transposes weights (fp32, for fixup) AND
//     pre-converts them to bf16 hi/lo planes [n][k] (nt folded into w). pass1<1>
//     stages B with wide loads (no conversion); A converted in-reg via truncation split.
//   MID tier  (ws >= ~54.5MB): round-5 structure (in-loop B conversion, transposed fixup).
//   LOW tier  (ws >= 1MB):     in-loop conversion, strided fixup.
//   else:                      full-fp64 vector kernel (known passing).
// pass2 fixup recomputes |v_next-theta_s|<DELTA elements in fp64 (exact spike decisions).

#define Mdim 4096
#define Ndim 2048
#define Kdim 2048          // per source; 3 sources
#define BM 128
#define BN 128
#define BK 32
#define LDT 40             // LDS row stride in bf16 elems (80B rows, 5 granules coprime to 8)
#define DELTA 2.0e-3f
#define PLE ((size_t)Kdim * Ndim)            // elems per plane

typedef __attribute__((ext_vector_type(8))) short bf16x8;
typedef __attribute__((ext_vector_type(4))) float f32x4;

__device__ __forceinline__ ushort f2bf_rne(float f) {
    uint u = __float_as_uint(f);
    uint r = u + 0x7FFFu + ((u >> 16) & 1u);
    return (ushort)(r >> 16);
}
__device__ __forceinline__ float bf2f(ushort h) {
    return __uint_as_float(((uint)h) << 16);
}
// truncation hi/lo split of 2 floats -> 2 packed uints (2 bf16 each, k-minor order)
__device__ __forceinline__ void split2(float f0, float f1, uint& H, uint& L) {
    uint u0 = __float_as_uint(f0), u1 = __float_as_uint(f1);
    H = (u0 >> 16) | (u1 & 0xFFFF0000u);
    float r0 = f0 - __uint_as_float(u0 & 0xFFFF0000u);
    float r1 = f1 - __uint_as_float(u1 & 0xFFFF0000u);
    L = (__float_as_uint(r0) >> 16) | (__float_as_uint(r1) & 0xFFFF0000u);
}

// ---------------- prep: transpose fp32 + bf16 hi/lo planes (nt folded into w) ----------
__global__ __launch_bounds__(256)
void nlif_prep(const float* __restrict__ w, const float* __restrict__ Wf,
               const float* __restrict__ Wi, const float* __restrict__ nt,
               float* __restrict__ wT, ushort* __restrict__ bpl)
{
    const int m = blockIdx.z;
    const float* src = (m == 0) ? w : (m == 1) ? Wf : Wi;
    float*  dT = wT + (size_t)m * PLE;
    ushort* bh = bpl + (size_t)(2 * m) * PLE;
    ushort* bl = bh + PLE;

    __shared__ float tile[32][33];
    const int bx = blockIdx.x * 32;     // n base
    const int by = blockIdx.y * 32;     // k base
    const int tx = threadIdx.x & 31, ty = threadIdx.x >> 5;

    #pragma unroll
    for (int i = 0; i < 4; ++i)
        tile[ty + 8 * i][tx] = src[(size_t)(by + ty + 8 * i) * Ndim + bx + tx];
    __syncthreads();

    const int k = by + tx;
    const float sc = (m == 0) ? nt[k] : 1.0f;
    #pragma unroll
    for (int i = 0; i < 4; ++i) {
        const int n = bx + ty + 8 * i;
        const float raw = tile[tx][ty + 8 * i];
        const size_t o = (size_t)n * Kdim + k;
        dT[o] = raw;                                  // fp32, nt NOT folded (fixup folds)
        const float vscaled = raw * sc;               // nt folded for MFMA planes
        uint u = __float_as_uint(vscaled);
        ushort h = (ushort)(u >> 16);
        float r = vscaled - __uint_as_float(u & 0xFFFF0000u);
        bh[o] = h;
        bl[o] = (ushort)(__float_as_uint(r) >> 16);
    }
}

// ---------------- pass 1: MFMA GEMM + epilogue + flagging ----------------
template<int PREB>
__global__ __launch_bounds__(256, 2)
void nlif_pass1(const float* __restrict__ I_ext,
                const float* __restrict__ v,
                const float* __restrict__ g,
                const float* __restrict__ g_fast,
                const float* __restrict__ s,
                const float* __restrict__ theta_s,
                const float* __restrict__ w,
                const float* __restrict__ W_fast,
                const float* __restrict__ W_in,
                const ushort* __restrict__ bpl,   // bf16 planes [n][k] (PREB=1)
                const float* __restrict__ I_tonic,
                const float* __restrict__ O,
                const float* __restrict__ nt,
                uint* __restrict__ counter,
                uint* __restrict__ wl, int cap,
                float* __restrict__ out)
{
    __shared__ ushort Ah[BM][LDT];   // A hi: [row][k]
    __shared__ ushort Al[BM][LDT];
    __shared__ ushort Bh[BN][LDT];   // B hi: [col][k]
    __shared__ ushort Bl[BN][LDT];

    const int t    = threadIdx.x;
    const int lane = t & 63;
    const int wid  = t >> 6;
    const int wr   = wid >> 1;
    const int wc   = wid & 1;

    // XCD-aware swizzle (512 blocks = 8 XCDs x 64, bijective)
    int lin = blockIdx.y * 16 + blockIdx.x;
    int swz = (lin & 7) * 64 + (lin >> 3);
    const int rowBase = (swz >> 4) * BM;
    const int colBase = (swz & 15) * BN;

    const float* aSrc[3] = {g, g_fast, I_ext};
    const float* bSrc[3] = {w, W_fast, W_in};

    f32x4 acc[4][4];
    #pragma unroll
    for (int i = 0; i < 4; ++i)
        #pragma unroll
        for (int j = 0; j < 4; ++j)
            acc[i][j] = (f32x4){0.f, 0.f, 0.f, 0.f};

    // staging registers
    float4 fA[4];                    // A: 16 fp32 (row rA, k hA..hA+15)
    uint   bHi[8], bLo[8];           // B (PREB=1): 16 bf16 per plane, packed pairs
    float  fB[16];                   // B (PREB=0)

    const int rA  = t >> 1;          // A row / (PREB=1) B col
    const int hA  = (t & 1) << 4;    // k half offset 0/16
    const int cB  = t & 127;         // (PREB=0) B col
    const int kgB = (t >> 7) << 4;   // (PREB=0) k group 0/16

    auto load_regs = [&](int tile) {
        const int sel = tile >> 6;
        const int kl  = (tile & 63) << 5;
        const float* Ap = aSrc[sel] + (size_t)(rowBase + rA) * Ndim + kl + hA;
        #pragma unroll
        for (int i = 0; i < 4; ++i) fA[i] = *(const float4*)(Ap + 4 * i);

        if constexpr (PREB) {
            const ushort* ph = bpl + (size_t)(2 * sel) * PLE
                             + (size_t)(colBase + rA) * Kdim + kl + hA;
            *(uint4*)&bHi[0] = *(const uint4*)ph;
            *(uint4*)&bHi[4] = *(const uint4*)(ph + 8);
            const ushort* pl = ph + PLE;
            *(uint4*)&bLo[0] = *(const uint4*)pl;
            *(uint4*)&bLo[4] = *(const uint4*)(pl + 8);
        } else {
            const float* Bp = bSrc[sel];
            if (sel == 0) {
                #pragma unroll
                for (int kk = 0; kk < 16; ++kk) {
                    int k = kl + kgB + kk;
                    fB[kk] = Bp[(size_t)k * Ndim + colBase + cB] * nt[k];
                }
            } else {
                #pragma unroll
                for (int kk = 0; kk < 16; ++kk) {
                    int k = kl + kgB + kk;
                    fB[kk] = Bp[(size_t)k * Ndim + colBase + cB];
                }
            }
        }
    };

    auto write_lds = [&]() {
        // A: truncation split, packed -> 2x b128 per plane
        uint aHi[8], aLo[8];
        #pragma unroll
        for (int i = 0; i < 4; ++i) {
            split2(fA[i].x, fA[i].y, aHi[2 * i],     aLo[2 * i]);
            split2(fA[i].z, fA[i].w, aHi[2 * i + 1], aLo[2 * i + 1]);
        }
        *(uint4*)&Ah[rA][hA]     = *(uint4*)&aHi[0];
        *(uint4*)&Ah[rA][hA + 8] = *(uint4*)&aHi[4];
        *(uint4*)&Al[rA][hA]     = *(uint4*)&aLo[0];
        *(uint4*)&Al[rA][hA + 8] = *(uint4*)&aLo[4];

        if constexpr (PREB) {
            *(uint4*)&Bh[rA][hA]     = *(uint4*)&bHi[0];
            *(uint4*)&Bh[rA][hA + 8] = *(uint4*)&bHi[4];
            *(uint4*)&Bl[rA][hA]     = *(uint4*)&bLo[0];
            *(uint4*)&Bl[rA][hA + 8] = *(uint4*)&bLo[4];
        } else {
            #pragma unroll
            for (int q = 0; q < 8; ++q) {
                uint H, L;
                split2(fB[2 * q], fB[2 * q + 1], H, L);
                *(uint*)&Bh[cB][kgB + 2 * q] = H;
                *(uint*)&Bl[cB][kgB + 2 * q] = L;
            }
        }
    };

    load_regs(0);
    write_lds();
    __syncthreads();

    const int NT = 3 * Kdim / BK;       // 192
    const int l15  = lane & 15;
    const int koff = (lane >> 4) << 3;

    for (int tile = 0; tile < NT; ++tile) {
        if (tile + 1 < NT) load_regs(tile + 1);

        bf16x8 ah[4], al[4], bh[4], bl[4];
        #pragma unroll
        for (int f = 0; f < 4; ++f) {
            int ar = wr * 64 + f * 16 + l15;
            ah[f] = *(const bf16x8*)&Ah[ar][koff];
            al[f] = *(const bf16x8*)&Al[ar][koff];
            int bc = wc * 64 + f * 16 + l15;
            bh[f] = *(const bf16x8*)&Bh[bc][koff];
            bl[f] = *(const bf16x8*)&Bl[bc][koff];
        }
        #pragma unroll
        for (int i = 0; i < 4; ++i)
            #pragma unroll
            for (int j = 0; j < 4; ++j) {
                acc[i][j] = __builtin_amdgcn_mfma_f32_16x16x32_bf16(ah[i], bh[j], acc[i][j], 0, 0, 0);
                acc[i][j] = __builtin_amdgcn_mfma_f32_16x16x32_bf16(ah[i], bl[j], acc[i][j], 0, 0, 0);
                acc[i][j] = __builtin_amdgcn_mfma_f32_16x16x32_bf16(al[i], bh[j], acc[i][j], 0, 0, 0);
            }

        if (tile + 1 < NT) {
            __syncthreads();
            write_lds();
            __syncthreads();
        }
    }

    // ---- fused fp32 epilogue; C/D layout: col=lane&15, row=(lane>>4)*4+p ----
    const size_t SLAB = (size_t)Mdim * Ndim;
    float* out_ro = out;
    float* out_v  = out + SLAB;
    float* out_g  = out + 2 * SLAB;
    float* out_gf = out + 3 * SLAB;
    float* out_s  = out + 4 * SLAB;
    float* out_th = out + 5 * SLAB;

    const int rowF = ((lane >> 4) << 2);
    #pragma unroll
    for (int i = 0; i < 4; ++i) {
        #pragma unroll
        for (int j = 0; j < 4; ++j) {
            int col = colBase + wc * 64 + j * 16 + l15;
            float ton = I_tonic[col];
            float ov  = O[col];
            #pragma unroll
            for (int p = 0; p < 4; ++p) {
                int row = rowBase + wr * 64 + i * 16 + rowF + p;
                size_t off = (size_t)row * Ndim + col;
                float Itot   = acc[i][j][p] + ton;
                float vv     = v[off];
                float dv     = (Itot - vv) * 0.1f;
                float v_next = vv + dv;
                float gating = fminf(fmaxf(v_next, 0.f), 1.f);
                float dvc    = fminf(fmaxf(dv, 0.f), 1.f);
                float sv     = s[off];
                float s_new  = sv + (gating * dvc - sv) * 0.1f;
                float th     = theta_s[off];
                bool  sp     = (v_next >= th);
                out_ro[off] = ov * s_new;
                out_v [off] = sp ? fmaf(0.14f, vv, -0.12f) : v_next;
                out_g [off] = sp ? 1.f : (-g[off] * 0.1f);
                out_gf[off] = sp ? 1.f : (-g_fast[off]);
                out_s [off] = s_new;
                out_th[off] = 0.7f * th + (sp ? 0.1f : 0.f);
                if (fabsf(v_next - th) < DELTA) {
                    uint idx = atomicAdd(counter, 1u);
                    if (idx < (uint)cap) wl[idx] = ((uint)row << 11) | (uint)col;
                }
            }
        }
    }
}

// ---------------- pass 2: fp64 fixup of flagged elements ----------------
__device__ __forceinline__ float ldw(const float* p, int c, int k, int tmode) {
    return tmode ? p[(size_t)c * Kdim + k] : p[(size_t)k * Ndim + c];
}

__global__ __launch_bounds__(256)
void nlif_fixup(const float* __restrict__ I_ext,
                const float* __restrict__ v,
                const float* __restrict__ g,
                const float* __restrict__ g_fast,
                const float* __restrict__ s,
                const float* __restrict__ theta_s,
                const float* __restrict__ w0,
                const float* __restrict__ w1,
                const float* __restrict__ w2,
                int tmode,
                const float* __restrict__ I_tonic,
                const float* __restrict__ O,
                const float* __restrict__ nt,
                const uint* __restrict__ counter,
                const uint* __restrict__ wl, int cap,
                float* __restrict__ out)
{
    uint cnt = *counter;
    int n = (int)(cnt < (uint)cap ? cnt : (uint)cap);
    int wgid = (int)((blockIdx.x * blockDim.x + threadIdx.x) >> 6);
    int lane = threadIdx.x & 63;
    int nw   = (int)((gridDim.x * blockDim.x) >> 6);
    const size_t SLAB = (size_t)Mdim * Ndim;

    for (int e = wgid; e < n; e += nw) {
        uint u = wl[e];
        int r = (int)(u >> 11), c = (int)(u & 2047);
        double acc = 0.0;
        for (int k = lane; k < Kdim; k += 64) {
            size_t ro = (size_t)r * Ndim + k;
            double wsyn = (double)ldw(w0, c, k, tmode) * (double)nt[k];
            acc += (double)g[ro] * wsyn;
            acc += (double)g_fast[ro] * (double)ldw(w1, c, k, tmode);
            acc += (double)I_ext[ro] * (double)ldw(w2, c, k, tmode);
        }
        #pragma unroll
        for (int m = 32; m; m >>= 1) acc += __shfl_xor(acc, m);

        if (lane == 0) {
            size_t off = (size_t)r * Ndim + c;
            double vv = (double)v[off], sv = (double)s[off], tv = (double)theta_s[off];
            double Itot   = acc + (double)I_tonic[c];
            double dvv    = (0.0 - vv + Itot) / 10.0;
            double v_next = vv + dvv;
            double gating = fmin(fmax(v_next, 0.0), 1.0);
            double dvc    = fmin(fmax(dvv, 0.0), 1.0);
            double s_new  = sv + (-sv + gating * dvc) / 10.0;
            bool   sp     = (v_next >= tv);
            out[off]            = (float)((double)O[c] * s_new);
            out[off + SLAB]     = (float)(sp ? (0.14 * vv - 0.12) : v_next);
            out[off + 2 * SLAB] = (float)(sp ? 1.0 : (-(double)g[off] / 10.0));
            out[off + 3 * SLAB] = (float)(sp ? 1.0 : -(double)g_fast[off]);
            out[off + 4 * SLAB] = (float)s_new;
            out[off + 5 * SLAB] = (float)(0.7 * tv + (sp ? 0.1 : 0.0));
        }
    }
}

// ---------------- helpers ----------------
__global__ void zero_cnt(uint* c) { *c = 0u; }

__global__ __launch_bounds__(256)
void transpose_k(const float* __restrict__ in, float* __restrict__ out) {
    __shared__ float tile[32][33];
    int bx = blockIdx.x * 32, by = blockIdx.y * 32;
    int tx = threadIdx.x & 31, ty = threadIdx.x >> 5;
    #pragma unroll
    for (int i = 0; i < 4; ++i)
        tile[ty + 8 * i][tx] = in[(size_t)(by + ty + 8 * i) * Ndim + bx + tx];
    __syncthreads();
    #pragma unroll
    for (int i = 0; i < 4; ++i)
        out[(size_t)(bx + ty + 8 * i) * Ndim + by + tx] = tile[tx][ty + 8 * i];
}

// ---------------- fallback: fp64 vector kernel (known-passing) ----------------
#define LDAF 132
#define LDBF 132
__global__ __launch_bounds__(256, 2)
void nlif_fp64(const float* __restrict__ I_ext, const float* __restrict__ v,
               const float* __restrict__ g, const float* __restrict__ g_fast,
               const float* __restrict__ s, const float* __restrict__ theta_s,
               const float* __restrict__ w, const float* __restrict__ W_fast,
               const float* __restrict__ W_in, const float* __restrict__ I_tonic,
               const float* __restrict__ O, const float* __restrict__ nt,
               float* __restrict__ out)
{
    __shared__ float As[BK][LDAF];
    __shared__ float Bs[BK][LDBF];
    const int t = threadIdx.x, tx = t & 15, ty = t >> 4;
    const int rowBase = blockIdx.y * BM, colBase = blockIdx.x * BN;
    const float* aSrc[3] = {g, g_fast, I_ext};
    const float* bSrc[3] = {w, W_fast, W_in};
    double acc[8][8];
    #pragma unroll
    for (int i = 0; i < 8; ++i)
        #pragma unroll
        for (int j = 0; j < 8; ++j) acc[i][j] = 0.0;
    float4 aReg[4], bReg[4];
    auto loadTile = [&](int tile) {
        const int sel = tile >> 6, kl = (tile & 63) << 5;
        const float* A = aSrc[sel]; const float* Bp = bSrc[sel];
        #pragma unroll
        for (int i = 0; i < 4; ++i) {
            int idx = t + 256 * i, r = idx >> 3, c4 = idx & 7;
            aReg[i] = *(const float4*)(A + (size_t)(rowBase + r) * Ndim + kl + c4 * 4);
        }
        #pragma unroll
        for (int i = 0; i < 4; ++i) {
            int idx = t + 256 * i, r = idx >> 5, c4 = idx & 31;
            float4 bv = *(const float4*)(Bp + (size_t)(kl + r) * Ndim + colBase + c4 * 4);
            if (sel == 0) { float sc = nt[kl + r]; bv.x *= sc; bv.y *= sc; bv.z *= sc; bv.w *= sc; }
            bReg[i] = bv;
        }
    };
    auto storeTile = [&]() {
        #pragma unroll
        for (int i = 0; i < 4; ++i) {
            int idx = t + 256 * i, r = idx >> 3, c = (idx & 7) * 4;
            As[c][r] = aReg[i].x; As[c + 1][r] = aReg[i].y;
            As[c + 2][r] = aReg[i].z; As[c + 3][r] = aReg[i].w;
        }
        #pragma unroll
        for (int i = 0; i < 4; ++i) {
            int idx = t + 256 * i, r = idx >> 5, c = (idx & 31) * 4;
            *(float4*)&Bs[r][c] = bReg[i];
        }
    };
    loadTile(0); storeTile(); __syncthreads();
    const int NT = 3 * Kdim / BK;
    for (int tile = 0; tile < NT; ++tile) {
        if (tile + 1 < NT) loadTile(tile + 1);
        #pragma unroll 8
        for (int k = 0; k < BK; ++k) {
            float4 a0 = *(const float4*)&As[k][ty * 4];
            float4 a1 = *(const float4*)&As[k][ty * 4 + 64];
            float4 b0 = *(const float4*)&Bs[k][tx * 4];
            float4 b1 = *(const float4*)&Bs[k][tx * 4 + 64];
            double ad[8] = {a0.x, a0.y, a0.z, a0.w, a1.x, a1.y, a1.z, a1.w};
            double bd[8] = {b0.x, b0.y, b0.z, b0.w, b1.x, b1.y, b1.z, b1.w};
            #pragma unroll
            for (int ri = 0; ri < 8; ++ri)
                #pragma unroll
                for (int cj = 0; cj < 8; ++cj)
                    acc[ri][cj] = fma(ad[ri], bd[cj], acc[ri][cj]);
        }
        if (tile + 1 < NT) { __syncthreads(); storeTile(); __syncthreads(); }
    }
    const size_t SLAB = (size_t)Mdim * Ndim;
    #pragma unroll
    for (int ri = 0; ri < 8; ++ri) {
        int row = rowBase + ty * 4 + (ri & 3) + ((ri >> 2) << 6);
        #pragma unroll
        for (int cg = 0; cg < 2; ++cg) {
            int col = colBase + tx * 4 + cg * 64;
            size_t off = (size_t)row * Ndim + col;
            #pragma unroll
            for (int e = 0; e < 4; ++e) {
                size_t o = off + e;
                double Itot   = acc[ri][cg * 4 + e] + (double)I_tonic[col + e];
                double vv = v[o], sv = s[o], tv = theta_s[o];
                double dvv    = (0.0 - vv + Itot) / 10.0;
                double v_next = vv + dvv;
                double gating = fmin(fmax(v_next, 0.0), 1.0);
                double dvc    = fmin(fmax(dvv, 0.0), 1.0);
                double s_new  = sv + (-sv + gating * dvc) / 10.0;
                bool   sp     = (v_next >= tv);
                out[o]            = (float)((double)O[col + e] * s_new);
                out[o + SLAB]     = (float)(sp ? (0.14 * vv - 0.12) : v_next);
                out[o + 2 * SLAB] = (float)(sp ? 1.0 : (-(double)g[o] / 10.0));
                out[o + 3 * SLAB] = (float)(sp ? 1.0 : -(double)g_fast[o]);
                out[o + 4 * SLAB] = (float)s_new;
                out[o + 5 * SLAB] = (float)(0.7 * tv + (sp ? 0.1 : 0.0));
            }
        }
    }
}

extern "C" void kernel_launch(void* const* d_in, const int* in_sizes, int n_in,
                              void* d_out, int out_size, void* d_ws, size_t ws_size,
                              hipStream_t stream) {
    const float* I_ext   = (const float*)d_in[0];
    const float* v       = (const float*)d_in[1];
    const float* g       = (const float*)d_in[2];
    const float* g_fast  = (const float*)d_in[3];
    const float* s       = (const float*)d_in[4];
    const float* theta_s = (const float*)d_in[5];
    const float* w       = (const float*)d_in[6];
    const float* W_fast  = (const float*)d_in[7];
    const float* W_in    = (const float*)d_in[8];
    const float* I_tonic = (const float*)d_in[9];
    const float* O       = (const float*)d_in[10];
    const float* nt      = (const float*)d_in[11];
    float* out           = (float*)d_out;

    const size_t WT_B  = 3 * PLE * sizeof(float);    // 50,331,648
    const size_t BPL_B = 6 * PLE * sizeof(ushort);   // 50,331,648
    const size_t WL_B  = (size_t)1 << 22;            // 4 MB worklist

    uint8_t* ws = (uint8_t*)d_ws;
    dim3 grid(Ndim / BN, Mdim / BM);                 // 512 blocks

    if (ws_size < (1u << 20) + 256) {                // no room -> known-good fp64 path
        nlif_fp64<<<grid, 256, 0, stream>>>(I_ext, v, g, g_fast, s, theta_s,
                                            w, W_fast, W_in, I_tonic, O, nt, out);
        return;
    }

    uint* counter = (uint*)ws;
    zero_cnt<<<1, 1, 0, stream>>>(counter);

    if (ws_size >= 256 + WT_B + BPL_B + WL_B) {
        // ---- FULL tier ----
        float*  wT  = (float*)(ws + 256);
        ushort* bpl = (ushort*)(ws + 256 + WT_B);
        uint*   wl  = (uint*)(ws + 256 + WT_B + BPL_B);
        int cap = (int)(WL_B / 4);

        dim3 pg(Ndim / 32, Kdim / 32, 3);
        nlif_prep<<<pg, 256, 0, stream>>>(w, W_fast, W_in, nt, wT, bpl);
        nlif_pass1<1><<<grid, 256, 0, stream>>>(I_ext, v, g, g_fast, s, theta_s,
                                                w, W_fast, W_in, bpl,
                                                I_tonic, O, nt, counter, wl, cap, out);
        nlif_fixup<<<256, 256, 0, stream>>>(I_ext, v, g, g_fast, s, theta_s,
                                            wT, wT + PLE, wT + 2 * PLE, 1,
                                            I_tonic, O, nt, counter, wl, cap, out);
    } else if (ws_size >= 256 + WT_B + (1u << 20)) {
        // ---- MID tier (round-5 structure) ----
        float* wT = (float*)(ws + 256);
        uint*  wl = (uint*)(ws + 256 + WT_B);
        size_t cap = (ws_size - 256 - WT_B) / 4;
        if (cap > (1u << 20)) cap = (1u << 20);

        dim3 tg(Ndim / 32, Kdim / 32);
        transpose_k<<<tg, 256, 0, stream>>>(w, wT);
        transpose_k<<<tg, 256, 0, stream>>>(W_fast, wT + PLE);
        transpose_k<<<tg, 256, 0, stream>>>(W_in, wT + 2 * PLE);
        nlif_pass1<0><<<grid, 256, 0, stream>>>(I_ext, v, g, g_fast, s, theta_s,
                                                w, W_fast, W_in, nullptr,
                                                I_tonic, O, nt, counter, wl, (int)cap, out);
        nlif_fixup<<<256, 256, 0, stream>>>(I_ext, v, g, g_fast, s, theta_s,
                                            wT, wT + PLE, wT + 2 * PLE, 1,
                                            I_tonic, O, nt, counter, wl, (int)cap, out);
    } else {
        // ---- LOW tier ----
        uint* wl = (uint*)(ws + 256);
        size_t cap = (ws_size - 256) / 4;
        if (cap > (1u << 20)) cap = (1u << 20);
        nlif_pass1<0><<<grid, 256, 0, stream>>>(I_ext, v, g, g_fast, s, theta_s,
                                                w, W_fast, W_in, nullptr,
                                                I_tonic, O, nt, counter, wl, (int)cap, out);
        nlif_fixup<<<256, 256, 0, stream>>>(I_ext, v, g, g_fast, s, theta_s,
                                            w, W_fast, W_in, 0,
                                            I_tonic, O, nt, counter, wl, (int)cap, out);
    }
}

// Round 8
// 840.459 us; speedup vs baseline: 1.6633x; 1.6633x over previous
//
#include <hip/hip_runtime.h>

// NLIF fused step, two-pass mixed precision.
//   prep:  transpose weights to [n][k] fp32 (for fixup) + RNE bf16 hi/lo planes
//          [n][k] (nt folded into w) for pass1's MFMA B operand.
//   pass1: bf16 hi/lo-split MFMA GEMM (hh+hl+lh). B staged via global_load_lds
//          (no staging registers -> no spill) into double-buffered LINEAR LDS with
//          granule XOR-swizzle (pre-swizzled global source + swizzled read, rule #21)
//          -> conflict-free b128 reads. A reg-staged + RNE split into padded [128][40].
//          Fused fp32 epilogue flags |v_next - theta_s| < DELTA (~1.4K of 8.4M).
//   pass2: fp64 recompute of flagged elements (exact spike decisions).
// Tiers degrade gracefully to the known-passing fp64 vector kernel.

#define Mdim 4096
#define Ndim 2048
#define Kdim 2048          // per source; 3 sources
#define BM 128
#define BN 128
#define BK 32
#define LDT 40             // A LDS row stride in ushorts (80B rows, 5 granules coprime to 8)
#define DELTA 2.0e-4f      // RNE-split v_next error: ~1e-5 typ, <1.5e-4 worst
#define PLE ((size_t)Kdim * Ndim)

typedef __attribute__((ext_vector_type(8))) short bf16x8;
typedef __attribute__((ext_vector_type(4))) float f32x4;

__device__ __forceinline__ ushort f2bf_rne(float f) {
    uint u = __float_as_uint(f);
    uint r = u + 0x7FFFu + ((u >> 16) & 1u);
    return (ushort)(r >> 16);
}
__device__ __forceinline__ float bf2f(ushort h) {
    return __uint_as_float(((uint)h) << 16);
}

// async 16B global->LDS (linear dest: wave-uniform base + lane*16)
__device__ __forceinline__ void gload16(const ushort* g, ushort* l) {
    __builtin_amdgcn_global_load_lds(
        (const __attribute__((address_space(1))) uint*)(uintptr_t)g,
        (__attribute__((address_space(3))) uint*)(uint32_t)(uintptr_t)l,
        16, 0, 0);
}

// ---------------- prep: fp32 transpose + RNE bf16 hi/lo planes (nt folded) ----------
__global__ __launch_bounds__(256)
void nlif_prep(const float* __restrict__ w, const float* __restrict__ Wf,
               const float* __restrict__ Wi, const float* __restrict__ nt,
               float* __restrict__ wT, ushort* __restrict__ bpl)
{
    const int m = blockIdx.z;
    const float* src = (m == 0) ? w : (m == 1) ? Wf : Wi;
    float*  dT = wT + (size_t)m * PLE;
    ushort* bh = bpl + (size_t)(2 * m) * PLE;
    ushort* bl = bh + PLE;

    __shared__ float tile[32][33];
    const int bx = blockIdx.x * 32;     // n base
    const int by = blockIdx.y * 32;     // k base
    const int tx = threadIdx.x & 31, ty = threadIdx.x >> 5;

    #pragma unroll
    for (int i = 0; i < 4; ++i)
        tile[ty + 8 * i][tx] = src[(size_t)(by + ty + 8 * i) * Ndim + bx + tx];
    __syncthreads();

    const int k = by + tx;
    const float sc = (m == 0) ? nt[k] : 1.0f;
    #pragma unroll
    for (int i = 0; i < 4; ++i) {
        const int n = bx + ty + 8 * i;
        const float raw = tile[tx][ty + 8 * i];
        const size_t o = (size_t)n * Kdim + k;
        dT[o] = raw;                                  // fp32, nt NOT folded (fixup folds)
        const float x = raw * sc;                     // nt folded for MFMA planes
        ushort h = f2bf_rne(x);
        bh[o] = h;
        bl[o] = f2bf_rne(x - bf2f(h));
    }
}

// ---------------- pass 1: MFMA GEMM + epilogue + flagging ----------------
template<int PREB>
__global__ __launch_bounds__(256, 2)
void nlif_pass1(const float* __restrict__ I_ext,
                const float* __restrict__ v,
                const float* __restrict__ g,
                const float* __restrict__ g_fast,
                const float* __restrict__ s,
                const float* __restrict__ theta_s,
                const float* __restrict__ w,
                const float* __restrict__ W_fast,
                const float* __restrict__ W_in,
                const ushort* __restrict__ bpl,   // bf16 planes [n][k] (PREB=1)
                const float* __restrict__ I_tonic,
                const float* __restrict__ O,
                const float* __restrict__ nt,
                uint* __restrict__ counter,
                uint* __restrict__ wl, int cap,
                float* __restrict__ out)
{
    __shared__ ushort Ah[BM][LDT];        // A hi: [row][k], padded
    __shared__ ushort Al[BM][LDT];
    __shared__ ushort Bh[2][BN * BK];     // B hi: flat slot*8 layout (gload_lds dest)
    __shared__ ushort Bl[2][BN * BK];

    const int t    = threadIdx.x;
    const int lane = t & 63;
    const int wid  = t >> 6;
    const int wr   = wid >> 1;
    const int wc   = wid & 1;

    // XCD-aware swizzle (512 blocks = 8 XCDs x 64, bijective)
    int lin = blockIdx.y * 16 + blockIdx.x;
    int swz = (lin & 7) * 64 + (lin >> 3);
    const int rowBase = (swz >> 4) * BM;
    const int colBase = (swz & 15) * BN;

    const float* aSrc[3] = {g, g_fast, I_ext};
    const float* bSrc[3] = {w, W_fast, W_in};

    f32x4 acc[4][4];
    #pragma unroll
    for (int i = 0; i < 4; ++i)
        #pragma unroll
        for (int j = 0; j < 4; ++j)
            acc[i][j] = (f32x4){0.f, 0.f, 0.f, 0.f};

    float4 fA[4];                    // A staging: 16 fp32
    float  fB[16];                   // B staging (PREB=0 only)

    const int rA  = t >> 1;          // A row
    const int hA  = (t & 1) << 4;    // A k half offset 0/16
    const int cB  = t & 127;         // (PREB=0) B col
    const int kgB = (t >> 7) << 4;   // (PREB=0) k group 0/16

    // B granule swizzle (PREB=1): store granule q of col at slot col*4 + (q^((col>>1)&3))
    const int qld = (lane & 3) ^ ((lane >> 3) & 3);      // granule this lane FETCHES

    auto issueB = [&](int tile) {    // PREB=1: async B stage, zero staging registers
        const int sel = tile >> 6;
        const int kl  = (tile & 63) << 5;
        const int buf = tile & 1;
        #pragma unroll
        for (int p = 0; p < 2; ++p) {
            const ushort* plane = bpl + (size_t)(2 * sel + p) * PLE;
            ushort* dBase = p ? &Bl[buf][0] : &Bh[buf][0];
            #pragma unroll
            for (int inst = 0; inst < 2; ++inst) {
                int col = wid * 32 + inst * 16 + (lane >> 2);
                const ushort* gsrc = plane + (size_t)(colBase + col) * Kdim + kl + qld * 8;
                ushort* ldst = dBase + (wid * 128 + inst * 64) * 8;   // wave-uniform
                gload16(gsrc, ldst);
            }
        }
    };

    auto loadRegs = [&](int tile) {
        const int sel = tile >> 6;
        const int kl  = (tile & 63) << 5;
        const float* Ap = aSrc[sel] + (size_t)(rowBase + rA) * Ndim + kl + hA;
        #pragma unroll
        for (int i = 0; i < 4; ++i) fA[i] = *(const float4*)(Ap + 4 * i);
        if constexpr (!PREB) {
            const float* Bp = bSrc[sel];
            if (sel == 0) {
                #pragma unroll
                for (int kk = 0; kk < 16; ++kk) {
                    int k = kl + kgB + kk;
                    fB[kk] = Bp[(size_t)k * Ndim + colBase + cB] * nt[k];
                }
            } else {
                #pragma unroll
                for (int kk = 0; kk < 16; ++kk) {
                    int k = kl + kgB + kk;
                    fB[kk] = Bp[(size_t)k * Ndim + colBase + cB];
                }
            }
        }
    };

    auto writeLds = [&](int tile) {
        #pragma unroll
        for (int i = 0; i < 4; ++i) {      // A: RNE hi/lo split
            float e[4] = {fA[i].x, fA[i].y, fA[i].z, fA[i].w};
            ushort4 hi, lo;
            ushort h0 = f2bf_rne(e[0]), h1 = f2bf_rne(e[1]),
                   h2 = f2bf_rne(e[2]), h3 = f2bf_rne(e[3]);
            hi.x = h0; hi.y = h1; hi.z = h2; hi.w = h3;
            lo.x = f2bf_rne(e[0] - bf2f(h0));
            lo.y = f2bf_rne(e[1] - bf2f(h1));
            lo.z = f2bf_rne(e[2] - bf2f(h2));
            lo.w = f2bf_rne(e[3] - bf2f(h3));
            *(ushort4*)&Ah[rA][hA + 4 * i] = hi;
            *(ushort4*)&Al[rA][hA + 4 * i] = lo;
        }
        if constexpr (!PREB) {             // linear layout, no swizzle
            const int buf = tile & 1;
            #pragma unroll
            for (int q = 0; q < 4; ++q) {
                ushort4 hi, lo;
                ushort h0 = f2bf_rne(fB[4*q+0]), h1 = f2bf_rne(fB[4*q+1]),
                       h2 = f2bf_rne(fB[4*q+2]), h3 = f2bf_rne(fB[4*q+3]);
                hi.x = h0; hi.y = h1; hi.z = h2; hi.w = h3;
                lo.x = f2bf_rne(fB[4*q+0] - bf2f(h0));
                lo.y = f2bf_rne(fB[4*q+1] - bf2f(h1));
                lo.z = f2bf_rne(fB[4*q+2] - bf2f(h2));
                lo.w = f2bf_rne(fB[4*q+3] - bf2f(h3));
                *(ushort4*)&Bh[buf][cB * BK + kgB + 4 * q] = hi;
                *(ushort4*)&Bl[buf][cB * BK + kgB + 4 * q] = lo;
            }
        }
    };

    if constexpr (PREB) issueB(0);
    loadRegs(0);
    writeLds(0);
    __syncthreads();          // drains gload_lds(0) + fA(0)

    const int NT = 3 * Kdim / BK;       // 192
    const int lo15 = lane & 15;
    const int hi4  = lane >> 4;
    const int koff = hi4 << 3;
    // read slot offset: col = wc*64 + f*16 + lo15; qslot = hi ^ ((lo>>1)&3) (PREB) or hi
    const int qs   = PREB ? (hi4 ^ ((lo15 >> 1) & 3)) : hi4;
    const int bOff = wc * 2048 + lo15 * 32 + qs * 8;     // + f*512 per fragment

    for (int tile = 0; tile < NT; ++tile) {
        if (tile + 1 < NT) {
            if constexpr (PREB) issueB(tile + 1);   // async into other buffer
            loadRegs(tile + 1);                     // A reg prefetch
        }
        const int buf = tile & 1;
        bf16x8 ah[4], al[4], bh4[4], bl4[4];
        #pragma unroll
        for (int f = 0; f < 4; ++f) {
            int ar = wr * 64 + f * 16 + lo15;
            ah[f] = *(const bf16x8*)&Ah[ar][koff];
            al[f] = *(const bf16x8*)&Al[ar][koff];
            bh4[f] = *(const bf16x8*)&Bh[buf][f * 512 + bOff];
            bl4[f] = *(const bf16x8*)&Bl[buf][f * 512 + bOff];
        }
        #pragma unroll
        for (int i = 0; i < 4; ++i)
            #pragma unroll
            for (int j = 0; j < 4; ++j) {
                acc[i][j] = __builtin_amdgcn_mfma_f32_16x16x32_bf16(ah[i], bh4[j], acc[i][j], 0, 0, 0);
                acc[i][j] = __builtin_amdgcn_mfma_f32_16x16x32_bf16(ah[i], bl4[j], acc[i][j], 0, 0, 0);
                acc[i][j] = __builtin_amdgcn_mfma_f32_16x16x32_bf16(al[i], bh4[j], acc[i][j], 0, 0, 0);
            }

        if (tile + 1 < NT) {
            __syncthreads();                // drains B(t+1) gloads + protects A rewrite
            writeLds(tile + 1);
            __syncthreads();
        }
    }

    // ---- fused fp32 epilogue; C/D layout: col=lane&15, row=(lane>>4)*4+p ----
    const size_t SLAB = (size_t)Mdim * Ndim;
    float* out_ro = out;
    float* out_v  = out + SLAB;
    float* out_g  = out + 2 * SLAB;
    float* out_gf = out + 3 * SLAB;
    float* out_s  = out + 4 * SLAB;
    float* out_th = out + 5 * SLAB;

    const int rowF = hi4 << 2;
    #pragma unroll
    for (int i = 0; i < 4; ++i) {
        #pragma unroll
        for (int j = 0; j < 4; ++j) {
            int col = colBase + wc * 64 + j * 16 + lo15;
            float ton = I_tonic[col];
            float ov  = O[col];
            #pragma unroll
            for (int p = 0; p < 4; ++p) {
                int row = rowBase + wr * 64 + i * 16 + rowF + p;
                size_t off = (size_t)row * Ndim + col;
                float Itot   = acc[i][j][p] + ton;
                float vv     = v[off];
                float dv     = (Itot - vv) * 0.1f;
                float v_next = vv + dv;
                float gating = fminf(fmaxf(v_next, 0.f), 1.f);
                float dvc    = fminf(fmaxf(dv, 0.f), 1.f);
                float sv     = s[off];
                float s_new  = sv + (gating * dvc - sv) * 0.1f;
                float th     = theta_s[off];
                bool  sp     = (v_next >= th);
                out_ro[off] = ov * s_new;
                out_v [off] = sp ? fmaf(0.14f, vv, -0.12f) : v_next;
                out_g [off] = sp ? 1.f : (-g[off] * 0.1f);
                out_gf[off] = sp ? 1.f : (-g_fast[off]);
                out_s [off] = s_new;
                out_th[off] = 0.7f * th + (sp ? 0.1f : 0.f);
                if (fabsf(v_next - th) < DELTA) {
                    uint idx = atomicAdd(counter, 1u);
                    if (idx < (uint)cap) wl[idx] = ((uint)row << 11) | (uint)col;
                }
            }
        }
    }
}

// ---------------- pass 2: fp64 fixup of flagged elements ----------------
__device__ __forceinline__ float ldw(const float* p, int c, int k, int tmode) {
    return tmode ? p[(size_t)c * Kdim + k] : p[(size_t)k * Ndim + c];
}

__global__ __launch_bounds__(256)
void nlif_fixup(const float* __restrict__ I_ext,
                const float* __restrict__ v,
                const float* __restrict__ g,
                const float* __restrict__ g_fast,
                const float* __restrict__ s,
                const float* __restrict__ theta_s,
                const float* __restrict__ w0,
                const float* __restrict__ w1,
                const float* __restrict__ w2,
                int tmode,
                const float* __restrict__ I_tonic,
                const float* __restrict__ O,
                const float* __restrict__ nt,
                const uint* __restrict__ counter,
                const uint* __restrict__ wl, int cap,
                float* __restrict__ out)
{
    uint cnt = *counter;
    int n = (int)(cnt < (uint)cap ? cnt : (uint)cap);
    int wgid = (int)((blockIdx.x * blockDim.x + threadIdx.x) >> 6);
    int lane = threadIdx.x & 63;
    int nw   = (int)((gridDim.x * blockDim.x) >> 6);
    const size_t SLAB = (size_t)Mdim * Ndim;

    for (int e = wgid; e < n; e += nw) {
        uint u = wl[e];
        int r = (int)(u >> 11), c = (int)(u & 2047);
        double acc = 0.0;
        for (int k = lane; k < Kdim; k += 64) {
            size_t ro = (size_t)r * Ndim + k;
            double wsyn = (double)ldw(w0, c, k, tmode) * (double)nt[k];
            acc += (double)g[ro] * wsyn;
            acc += (double)g_fast[ro] * (double)ldw(w1, c, k, tmode);
            acc += (double)I_ext[ro] * (double)ldw(w2, c, k, tmode);
        }
        #pragma unroll
        for (int m = 32; m; m >>= 1) acc += __shfl_xor(acc, m);

        if (lane == 0) {
            size_t off = (size_t)r * Ndim + c;
            double vv = (double)v[off], sv = (double)s[off], tv = (double)theta_s[off];
            double Itot   = acc + (double)I_tonic[c];
            double dvv    = (0.0 - vv + Itot) / 10.0;
            double v_next = vv + dvv;
            double gating = fmin(fmax(v_next, 0.0), 1.0);
            double dvc    = fmin(fmax(dvv, 0.0), 1.0);
            double s_new  = sv + (-sv + gating * dvc) / 10.0;
            bool   sp     = (v_next >= tv);
            out[off]            = (float)((double)O[c] * s_new);
            out[off + SLAB]     = (float)(sp ? (0.14 * vv - 0.12) : v_next);
            out[off + 2 * SLAB] = (float)(sp ? 1.0 : (-(double)g[off] / 10.0));
            out[off + 3 * SLAB] = (float)(sp ? 1.0 : -(double)g_fast[off]);
            out[off + 4 * SLAB] = (float)s_new;
            out[off + 5 * SLAB] = (float)(0.7 * tv + (sp ? 0.1 : 0.0));
        }
    }
}

// ---------------- helpers ----------------
__global__ void zero_cnt(uint* c) { *c = 0u; }

__global__ __launch_bounds__(256)
void transpose_k(const float* __restrict__ in, float* __restrict__ out) {
    __shared__ float tile[32][33];
    int bx = blockIdx.x * 32, by = blockIdx.y * 32;
    int tx = threadIdx.x & 31, ty = threadIdx.x >> 5;
    #pragma unroll
    for (int i = 0; i < 4; ++i)
        tile[ty + 8 * i][tx] = in[(size_t)(by + ty + 8 * i) * Ndim + bx + tx];
    __syncthreads();
    #pragma unroll
    for (int i = 0; i < 4; ++i)
        out[(size_t)(bx + ty + 8 * i) * Ndim + by + tx] = tile[tx][ty + 8 * i];
}

// ---------------- fallback: fp64 vector kernel (known-passing) ----------------
#define LDAF 132
#define LDBF 132
__global__ __launch_bounds__(256, 2)
void nlif_fp64(const float* __restrict__ I_ext, const float* __restrict__ v,
               const float* __restrict__ g, const float* __restrict__ g_fast,
               const float* __restrict__ s, const float* __restrict__ theta_s,
               const float* __restrict__ w, const float* __restrict__ W_fast,
               const float* __restrict__ W_in, const float* __restrict__ I_tonic,
               const float* __restrict__ O, const float* __restrict__ nt,
               float* __restrict__ out)
{
    __shared__ float As[BK][LDAF];
    __shared__ float Bs[BK][LDBF];
    const int t = threadIdx.x, tx = t & 15, ty = t >> 4;
    const int rowBase = blockIdx.y * BM, colBase = blockIdx.x * BN;
    const float* aSrc[3] = {g, g_fast, I_ext};
    const float* bSrc[3] = {w, W_fast, W_in};
    double acc[8][8];
    #pragma unroll
    for (int i = 0; i < 8; ++i)
        #pragma unroll
        for (int j = 0; j < 8; ++j) acc[i][j] = 0.0;
    float4 aReg[4], bReg[4];
    auto loadTile = [&](int tile) {
        const int sel = tile >> 6, kl = (tile & 63) << 5;
        const float* A = aSrc[sel]; const float* Bp = bSrc[sel];
        #pragma unroll
        for (int i = 0; i < 4; ++i) {
            int idx = t + 256 * i, r = idx >> 3, c4 = idx & 7;
            aReg[i] = *(const float4*)(A + (size_t)(rowBase + r) * Ndim + kl + c4 * 4);
        }
        #pragma unroll
        for (int i = 0; i < 4; ++i) {
            int idx = t + 256 * i, r = idx >> 5, c4 = idx & 31;
            float4 bv = *(const float4*)(Bp + (size_t)(kl + r) * Ndim + colBase + c4 * 4);
            if (sel == 0) { float sc = nt[kl + r]; bv.x *= sc; bv.y *= sc; bv.z *= sc; bv.w *= sc; }
            bReg[i] = bv;
        }
    };
    auto storeTile = [&]() {
        #pragma unroll
        for (int i = 0; i < 4; ++i) {
            int idx = t + 256 * i, r = idx >> 3, c = (idx & 7) * 4;
            As[c][r] = aReg[i].x; As[c + 1][r] = aReg[i].y;
            As[c + 2][r] = aReg[i].z; As[c + 3][r] = aReg[i].w;
        }
        #pragma unroll
        for (int i = 0; i < 4; ++i) {
            int idx = t + 256 * i, r = idx >> 5, c = (idx & 31) * 4;
            *(float4*)&Bs[r][c] = bReg[i];
        }
    };
    loadTile(0); storeTile(); __syncthreads();
    const int NT = 3 * Kdim / BK;
    for (int tile = 0; tile < NT; ++tile) {
        if (tile + 1 < NT) loadTile(tile + 1);
        #pragma unroll 8
        for (int k = 0; k < BK; ++k) {
            float4 a0 = *(const float4*)&As[k][ty * 4];
            float4 a1 = *(const float4*)&As[k][ty * 4 + 64];
            float4 b0 = *(const float4*)&Bs[k][tx * 4];
            float4 b1 = *(const float4*)&Bs[k][tx * 4 + 64];
            double ad[8] = {a0.x, a0.y, a0.z, a0.w, a1.x, a1.y, a1.z, a1.w};
            double bd[8] = {b0.x, b0.y, b0.z, b0.w, b1.x, b1.y, b1.z, b1.w};
            #pragma unroll
            for (int ri = 0; ri < 8; ++ri)
                #pragma unroll
                for (int cj = 0; cj < 8; ++cj)
                    acc[ri][cj] = fma(ad[ri], bd[cj], acc[ri][cj]);
        }
        if (tile + 1 < NT) { __syncthreads(); storeTile(); __syncthreads(); }
    }
    const size_t SLAB = (size_t)Mdim * Ndim;
    #pragma unroll
    for (int ri = 0; ri < 8; ++ri) {
        int row = rowBase + ty * 4 + (ri & 3) + ((ri >> 2) << 6);
        #pragma unroll
        for (int cg = 0; cg < 2; ++cg) {
            int col = colBase + tx * 4 + cg * 64;
            size_t off = (size_t)row * Ndim + col;
            #pragma unroll
            for (int e = 0; e < 4; ++e) {
                size_t o = off + e;
                double Itot   = acc[ri][cg * 4 + e] + (double)I_tonic[col + e];
                double vv = v[o], sv = s[o], tv = theta_s[o];
                double dvv    = (0.0 - vv + Itot) / 10.0;
                double v_next = vv + dvv;
                double gating = fmin(fmax(v_next, 0.0), 1.0);
                double dvc    = fmin(fmax(dvv, 0.0), 1.0);
                double s_new  = sv + (-sv + gating * dvc) / 10.0;
                bool   sp     = (v_next >= tv);
                out[o]            = (float)((double)O[col + e] * s_new);
                out[o + SLAB]     = (float)(sp ? (0.14 * vv - 0.12) : v_next);
                out[o + 2 * SLAB] = (float)(sp ? 1.0 : (-(double)g[o] / 10.0));
                out[o + 3 * SLAB] = (float)(sp ? 1.0 : -(double)g_fast[o]);
                out[o + 4 * SLAB] = (float)s_new;
                out[o + 5 * SLAB] = (float)(0.7 * tv + (sp ? 0.1 : 0.0));
            }
        }
    }
}

extern "C" void kernel_launch(void* const* d_in, const int* in_sizes, int n_in,
                              void* d_out, int out_size, void* d_ws, size_t ws_size,
                              hipStream_t stream) {
    const float* I_ext   = (const float*)d_in[0];
    const float* v       = (const float*)d_in[1];
    const float* g       = (const float*)d_in[2];
    const float* g_fast  = (const float*)d_in[3];
    const float* s       = (const float*)d_in[4];
    const float* theta_s = (const float*)d_in[5];
    const float* w       = (const float*)d_in[6];
    const float* W_fast  = (const float*)d_in[7];
    const float* W_in    = (const float*)d_in[8];
    const float* I_tonic = (const float*)d_in[9];
    const float* O       = (const float*)d_in[10];
    const float* nt      = (const float*)d_in[11];
    float* out           = (float*)d_out;

    const size_t WT_B  = 3 * PLE * sizeof(float);    // 50.3 MB
    const size_t BPL_B = 6 * PLE * sizeof(ushort);   // 50.3 MB
    const size_t WL_B  = (size_t)1 << 22;            // 4 MB worklist

    uint8_t* ws = (uint8_t*)d_ws;
    dim3 grid(Ndim / BN, Mdim / BM);                 // 512 blocks

    if (ws_size < (1u << 20) + 256) {                // no room -> known-good fp64 path
        nlif_fp64<<<grid, 256, 0, stream>>>(I_ext, v, g, g_fast, s, theta_s,
                                            w, W_fast, W_in, I_tonic, O, nt, out);
        return;
    }

    uint* counter = (uint*)ws;
    zero_cnt<<<1, 1, 0, stream>>>(counter);

    if (ws_size >= 256 + WT_B + BPL_B + WL_B) {
        // ---- FULL tier ----
        float*  wT  = (float*)(ws + 256);
        ushort* bpl = (ushort*)(ws + 256 + WT_B);
        uint*   wl  = (uint*)(ws + 256 + WT_B + BPL_B);
        int cap = (int)(WL_B / 4);

        dim3 pg(Ndim / 32, Kdim / 32, 3);
        nlif_prep<<<pg, 256, 0, stream>>>(w, W_fast, W_in, nt, wT, bpl);
        nlif_pass1<1><<<grid, 256, 0, stream>>>(I_ext, v, g, g_fast, s, theta_s,
                                                w, W_fast, W_in, bpl,
                                                I_tonic, O, nt, counter, wl, cap, out);
        nlif_fixup<<<256, 256, 0, stream>>>(I_ext, v, g, g_fast, s, theta_s,
                                            wT, wT + PLE, wT + 2 * PLE, 1,
                                            I_tonic, O, nt, counter, wl, cap, out);
    } else if (ws_size >= 256 + WT_B + (1u << 20)) {
        // ---- MID tier ----
        float* wT = (float*)(ws + 256);
        uint*  wl = (uint*)(ws + 256 + WT_B);
        size_t cap = (ws_size - 256 - WT_B) / 4;
        if (cap > (1u << 20)) cap = (1u << 20);

        dim3 tg(Ndim / 32, Kdim / 32);
        transpose_k<<<tg, 256, 0, stream>>>(w, wT);
        transpose_k<<<tg, 256, 0, stream>>>(W_fast, wT + PLE);
        transpose_k<<<tg, 256, 0, stream>>>(W_in, wT + 2 * PLE);
        nlif_pass1<0><<<grid, 256, 0, stream>>>(I_ext, v, g, g_fast, s, theta_s,
                                                w, W_fast, W_in, nullptr,
                                                I_tonic, O, nt, counter, wl, (int)cap, out);
        nlif_fixup<<<256, 256, 0, stream>>>(I_ext, v, g, g_fast, s, theta_s,
                                            wT, wT + PLE, wT + 2 * PLE, 1,
                                            I_tonic, O, nt, counter, wl, (int)cap, out);
    } else {
        // ---- LOW tier ----
        uint* wl = (uint*)(ws + 256);
        size_t cap = (ws_size - 256) / 4;
        if (cap > (1u << 20)) cap = (1u << 20);
        nlif_pass1<0><<<grid, 256, 0, stream>>>(I_ext, v, g, g_fast, s, theta_s,
                                                w, W_fast, W_in, nullptr,
                                                I_tonic, O, nt, counter, wl, (int)cap, out);
        nlif_fixup<<<256, 256, 0, stream>>>(I_ext, v, g, g_fast, s, theta_s,
                                            w, W_fast, W_in, 0,
                                            I_tonic, O, nt, counter, wl, (int)cap, out);
    }
}

// Round 9
// 776.827 us; speedup vs baseline: 1.7995x; 1.0819x over previous
//
#include <hip/hip_runtime.h>

// NLIF fused step, two-pass mixed precision.
//   prep:   weights -> fp32 transpose [n][k] (fixup) + RNE bf16 hi/lo planes [n][k]
//           (nt folded into w) for pass1 B.
//   prep2:  activations (g, g_fast, I_ext) -> RNE bf16 hi/lo planes [row][k] for pass1 A.
//   pass1_dma: bf16 hi/lo MFMA GEMM (hh+hl+lh); BOTH A and B staged via
//           global_load_lds with granule-XOR swizzle (pre-swizzled global source +
//           swizzled read) -> conflict-free b128 reads, ZERO conversion VALU and
//           ZERO ds_writes in the k-loop; ONE barrier per tile. Fused fp32 epilogue
//           flags |v_next - theta_s| < DELTA (~1.4K of 8.4M).
//   pass2:  fp64 recompute of flagged elements (exact spike decisions).
// Tiers: FULL2 (A+B DMA) > FULL (round-8: B DMA, A in-loop) > MID > LOW > fp64.

#define Mdim 4096
#define Ndim 2048
#define Kdim 2048          // per source; 3 sources
#define BM 128
#define BN 128
#define BK 32
#define LDT 40             // A LDS row stride (FULL tier only)
#define DELTA 2.0e-4f
#define PLE  ((size_t)Kdim * Ndim)   // weight plane elems
#define APLE ((size_t)Mdim * Ndim)   // activation plane elems

typedef __attribute__((ext_vector_type(8))) short bf16x8;
typedef __attribute__((ext_vector_type(4))) float f32x4;

__device__ __forceinline__ ushort f2bf_rne(float f) {
    uint u = __float_as_uint(f);
    uint r = u + 0x7FFFu + ((u >> 16) & 1u);
    return (ushort)(r >> 16);
}
__device__ __forceinline__ float bf2f(ushort h) {
    return __uint_as_float(((uint)h) << 16);
}

__device__ __forceinline__ void gload16(const ushort* g, ushort* l) {
    __builtin_amdgcn_global_load_lds(
        (const __attribute__((address_space(1))) uint*)(uintptr_t)g,
        (__attribute__((address_space(3))) uint*)(uint32_t)(uintptr_t)l,
        16, 0, 0);
}

// ---------------- prep: weights -> fp32 T + bf16 hi/lo planes (nt folded) ----------
__global__ __launch_bounds__(256)
void nlif_prep(const float* __restrict__ w, const float* __restrict__ Wf,
               const float* __restrict__ Wi, const float* __restrict__ nt,
               float* __restrict__ wT, ushort* __restrict__ bpl)
{
    const int m = blockIdx.z;
    const float* src = (m == 0) ? w : (m == 1) ? Wf : Wi;
    float*  dT = wT + (size_t)m * PLE;
    ushort* bh = bpl + (size_t)(2 * m) * PLE;
    ushort* bl = bh + PLE;

    __shared__ float tile[32][33];
    const int bx = blockIdx.x * 32;     // n base
    const int by = blockIdx.y * 32;     // k base
    const int tx = threadIdx.x & 31, ty = threadIdx.x >> 5;

    #pragma unroll
    for (int i = 0; i < 4; ++i)
        tile[ty + 8 * i][tx] = src[(size_t)(by + ty + 8 * i) * Ndim + bx + tx];
    __syncthreads();

    const int k = by + tx;
    const float sc = (m == 0) ? nt[k] : 1.0f;
    #pragma unroll
    for (int i = 0; i < 4; ++i) {
        const int n = bx + ty + 8 * i;
        const float raw = tile[tx][ty + 8 * i];
        const size_t o = (size_t)n * Kdim + k;
        dT[o] = raw;
        const float x = raw * sc;
        ushort h = f2bf_rne(x);
        bh[o] = h;
        bl[o] = f2bf_rne(x - bf2f(h));
    }
}

// ---------------- prep2: activations -> bf16 hi/lo planes (streaming) ----------
__global__ __launch_bounds__(256)
void nlif_prep2(const float* __restrict__ g, const float* __restrict__ g_fast,
                const float* __restrict__ I_ext, ushort* __restrict__ apl)
{
    size_t gid = (size_t)blockIdx.x * 256 + threadIdx.x;   // 3 * 2^20 threads
    int    sel = (int)(gid >> 20);
    size_t off = (gid & 1048575u) * 8;
    const float* src = (sel == 0) ? g : (sel == 1) ? g_fast : I_ext;
    float4 v0 = *(const float4*)(src + off);
    float4 v1 = *(const float4*)(src + off + 4);
    float e[8] = {v0.x, v0.y, v0.z, v0.w, v1.x, v1.y, v1.z, v1.w};
    ushort h[8], l[8];
    #pragma unroll
    for (int j = 0; j < 8; ++j) {
        h[j] = f2bf_rne(e[j]);
        l[j] = f2bf_rne(e[j] - bf2f(h[j]));
    }
    ushort* dh = apl + (size_t)(2 * sel) * APLE + off;
    ushort* dl = dh + APLE;
    *(uint4*)dh = *(uint4*)h;
    *(uint4*)dl = *(uint4*)l;
}

// ---------------- shared epilogue ----------------
__device__ __forceinline__ void epilogue(
    const f32x4 (&acc)[4][4], int rowBase, int colBase, int wr, int wc,
    int lo15, int hi4,
    const float* v, const float* s, const float* theta_s,
    const float* g, const float* g_fast,
    const float* I_tonic, const float* O,
    uint* counter, uint* wl, int cap, float* out)
{
    const size_t SLAB = (size_t)Mdim * Ndim;
    float* out_ro = out;
    float* out_v  = out + SLAB;
    float* out_g  = out + 2 * SLAB;
    float* out_gf = out + 3 * SLAB;
    float* out_s  = out + 4 * SLAB;
    float* out_th = out + 5 * SLAB;
    const int rowF = hi4 << 2;
    #pragma unroll
    for (int i = 0; i < 4; ++i) {
        #pragma unroll
        for (int j = 0; j < 4; ++j) {
            int col = colBase + wc * 64 + j * 16 + lo15;
            float ton = I_tonic[col];
            float ov  = O[col];
            #pragma unroll
            for (int p = 0; p < 4; ++p) {
                int row = rowBase + wr * 64 + i * 16 + rowF + p;
                size_t off = (size_t)row * Ndim + col;
                float Itot   = acc[i][j][p] + ton;
                float vv     = v[off];
                float dv     = (Itot - vv) * 0.1f;
                float v_next = vv + dv;
                float gating = fminf(fmaxf(v_next, 0.f), 1.f);
                float dvc    = fminf(fmaxf(dv, 0.f), 1.f);
                float sv     = s[off];
                float s_new  = sv + (gating * dvc - sv) * 0.1f;
                float th     = theta_s[off];
                bool  sp     = (v_next >= th);
                out_ro[off] = ov * s_new;
                out_v [off] = sp ? fmaf(0.14f, vv, -0.12f) : v_next;
                out_g [off] = sp ? 1.f : (-g[off] * 0.1f);
                out_gf[off] = sp ? 1.f : (-g_fast[off]);
                out_s [off] = s_new;
                out_th[off] = 0.7f * th + (sp ? 0.1f : 0.f);
                if (fabsf(v_next - th) < DELTA) {
                    uint idx = atomicAdd(counter, 1u);
                    if (idx < (uint)cap) wl[idx] = ((uint)row << 11) | (uint)col;
                }
            }
        }
    }
}

// ---------------- pass1 FULL2: A+B both via global_load_lds ----------------
__global__ __launch_bounds__(256, 2)
void nlif_pass1_dma(const float* __restrict__ v,
                    const float* __restrict__ g,
                    const float* __restrict__ g_fast,
                    const float* __restrict__ s,
                    const float* __restrict__ theta_s,
                    const ushort* __restrict__ apl,   // [2*sel+p][row][k]
                    const ushort* __restrict__ bpl,   // [2*sel+p][col][k]
                    const float* __restrict__ I_tonic,
                    const float* __restrict__ O,
                    uint* __restrict__ counter,
                    uint* __restrict__ wl, int cap,
                    float* __restrict__ out)
{
    __shared__ ushort Abuf[2][2][BM * BK];   // [plane][buf] 8KB each -> 32KB
    __shared__ ushort Bbuf[2][2][BN * BK];   // 32KB

    const int t    = threadIdx.x;
    const int lane = t & 63;
    const int wid  = t >> 6;
    const int wr   = wid >> 1;
    const int wc   = wid & 1;

    int lin = blockIdx.y * 16 + blockIdx.x;
    int swz = (lin & 7) * 64 + (lin >> 3);
    const int rowBase = (swz >> 4) * BM;
    const int colBase = (swz & 15) * BN;

    f32x4 acc[4][4];
    #pragma unroll
    for (int i = 0; i < 4; ++i)
        #pragma unroll
        for (int j = 0; j < 4; ++j)
            acc[i][j] = (f32x4){0.f, 0.f, 0.f, 0.f};

    // granule this lane FETCHES so that slot r*4+j holds granule j^((r>>1)&3)
    const int qld = (lane & 3) ^ ((lane >> 3) & 3);
    const int rr  = (lane >> 2);             // + wid*32 + inst*16

    auto issue = [&](int tile) {
        const int sel = tile >> 6;
        const int kl  = (tile & 63) << 5;
        const int buf = tile & 1;
        #pragma unroll
        for (int p = 0; p < 2; ++p) {
            const ushort* ap = apl + (size_t)(2 * sel + p) * APLE;
            const ushort* bp = bpl + (size_t)(2 * sel + p) * PLE;
            #pragma unroll
            for (int inst = 0; inst < 2; ++inst) {
                int r = wid * 32 + inst * 16 + rr;
                ushort* ldsOff = (ushort*)(size_t)((wid * 128 + inst * 64) * 8);
                gload16(ap + (size_t)(rowBase + r) * Kdim + kl + qld * 8,
                        &Abuf[p][buf][0] + (size_t)ldsOff);
                gload16(bp + (size_t)(colBase + r) * Kdim + kl + qld * 8,
                        &Bbuf[p][buf][0] + (size_t)ldsOff);
            }
        }
    };

    issue(0);
    __syncthreads();                       // drains tile-0 DMA

    const int NT = 3 * Kdim / BK;          // 192
    const int lo15 = lane & 15;
    const int hi4  = lane >> 4;
    const int qs   = hi4 ^ ((lo15 >> 1) & 3);
    const int aBase = wr * 2048 + lo15 * 32 + qs * 8;   // + f*512
    const int bBase = wc * 2048 + lo15 * 32 + qs * 8;

    for (int tile = 0; tile < NT; ++tile) {
        if (tile + 1 < NT) issue(tile + 1);    // DMA into other buffer
        const int buf = tile & 1;
        bf16x8 ah[4], al[4], bh[4], bl[4];
        #pragma unroll
        for (int f = 0; f < 4; ++f) {
            ah[f] = *(const bf16x8*)&Abuf[0][buf][f * 512 + aBase];
            al[f] = *(const bf16x8*)&Abuf[1][buf][f * 512 + aBase];
            bh[f] = *(const bf16x8*)&Bbuf[0][buf][f * 512 + bBase];
            bl[f] = *(const bf16x8*)&Bbuf[1][buf][f * 512 + bBase];
        }
        #pragma unroll
        for (int i = 0; i < 4; ++i)
            #pragma unroll
            for (int j = 0; j < 4; ++j) {
                acc[i][j] = __builtin_amdgcn_mfma_f32_16x16x32_bf16(ah[i], bh[j], acc[i][j], 0, 0, 0);
                acc[i][j] = __builtin_amdgcn_mfma_f32_16x16x32_bf16(ah[i], bl[j], acc[i][j], 0, 0, 0);
                acc[i][j] = __builtin_amdgcn_mfma_f32_16x16x32_bf16(al[i], bh[j], acc[i][j], 0, 0, 0);
            }
        __syncthreads();                   // drains (t+1) DMA; releases buf for reuse
    }

    epilogue(acc, rowBase, colBase, wr, wc, lo15, hi4,
             v, s, theta_s, g, g_fast, I_tonic, O, counter, wl, cap, out);
}

// ---------------- pass1 FULL/MID/LOW (round-8 proven) ----------------
template<int PREB>
__global__ __launch_bounds__(256, 2)
void nlif_pass1(const float* __restrict__ I_ext,
                const float* __restrict__ v,
                const float* __restrict__ g,
                const float* __restrict__ g_fast,
                const float* __restrict__ s,
                const float* __restrict__ theta_s,
                const float* __restrict__ w,
                const float* __restrict__ W_fast,
                const float* __restrict__ W_in,
                const ushort* __restrict__ bpl,
                const float* __restrict__ I_tonic,
                const float* __restrict__ O,
                const float* __restrict__ nt,
                uint* __restrict__ counter,
                uint* __restrict__ wl, int cap,
                float* __restrict__ out)
{
    __shared__ ushort Ah[BM][LDT];
    __shared__ ushort Al[BM][LDT];
    __shared__ ushort Bh[2][BN * BK];
    __shared__ ushort Bl[2][BN * BK];

    const int t    = threadIdx.x;
    const int lane = t & 63;
    const int wid  = t >> 6;
    const int wr   = wid >> 1;
    const int wc   = wid & 1;

    int lin = blockIdx.y * 16 + blockIdx.x;
    int swz = (lin & 7) * 64 + (lin >> 3);
    const int rowBase = (swz >> 4) * BM;
    const int colBase = (swz & 15) * BN;

    const float* aSrc[3] = {g, g_fast, I_ext};
    const float* bSrc[3] = {w, W_fast, W_in};

    f32x4 acc[4][4];
    #pragma unroll
    for (int i = 0; i < 4; ++i)
        #pragma unroll
        for (int j = 0; j < 4; ++j)
            acc[i][j] = (f32x4){0.f, 0.f, 0.f, 0.f};

    float4 fA[4];
    float  fB[16];

    const int rA  = t >> 1;
    const int hA  = (t & 1) << 4;
    const int cB  = t & 127;
    const int kgB = (t >> 7) << 4;
    const int qld = (lane & 3) ^ ((lane >> 3) & 3);

    auto issueB = [&](int tile) {
        const int sel = tile >> 6;
        const int kl  = (tile & 63) << 5;
        const int buf = tile & 1;
        #pragma unroll
        for (int p = 0; p < 2; ++p) {
            const ushort* plane = bpl + (size_t)(2 * sel + p) * PLE;
            ushort* dBase = p ? &Bl[buf][0] : &Bh[buf][0];
            #pragma unroll
            for (int inst = 0; inst < 2; ++inst) {
                int col = wid * 32 + inst * 16 + (lane >> 2);
                gload16(plane + (size_t)(colBase + col) * Kdim + kl + qld * 8,
                        dBase + (wid * 128 + inst * 64) * 8);
            }
        }
    };

    auto loadRegs = [&](int tile) {
        const int sel = tile >> 6;
        const int kl  = (tile & 63) << 5;
        const float* Ap = aSrc[sel] + (size_t)(rowBase + rA) * Ndim + kl + hA;
        #pragma unroll
        for (int i = 0; i < 4; ++i) fA[i] = *(const float4*)(Ap + 4 * i);
        if constexpr (!PREB) {
            const float* Bp = bSrc[sel];
            if (sel == 0) {
                #pragma unroll
                for (int kk = 0; kk < 16; ++kk) {
                    int k = kl + kgB + kk;
                    fB[kk] = Bp[(size_t)k * Ndim + colBase + cB] * nt[k];
                }
            } else {
                #pragma unroll
                for (int kk = 0; kk < 16; ++kk) {
                    int k = kl + kgB + kk;
                    fB[kk] = Bp[(size_t)k * Ndim + colBase + cB];
                }
            }
        }
    };

    auto writeLds = [&](int tile) {
        #pragma unroll
        for (int i = 0; i < 4; ++i) {
            float e[4] = {fA[i].x, fA[i].y, fA[i].z, fA[i].w};
            ushort4 hi, lo;
            ushort h0 = f2bf_rne(e[0]), h1 = f2bf_rne(e[1]),
                   h2 = f2bf_rne(e[2]), h3 = f2bf_rne(e[3]);
            hi.x = h0; hi.y = h1; hi.z = h2; hi.w = h3;
            lo.x = f2bf_rne(e[0] - bf2f(h0));
            lo.y = f2bf_rne(e[1] - bf2f(h1));
            lo.z = f2bf_rne(e[2] - bf2f(h2));
            lo.w = f2bf_rne(e[3] - bf2f(h3));
            *(ushort4*)&Ah[rA][hA + 4 * i] = hi;
            *(ushort4*)&Al[rA][hA + 4 * i] = lo;
        }
        if constexpr (!PREB) {
            const int buf = tile & 1;
            #pragma unroll
            for (int q = 0; q < 4; ++q) {
                ushort4 hi, lo;
                ushort h0 = f2bf_rne(fB[4*q+0]), h1 = f2bf_rne(fB[4*q+1]),
                       h2 = f2bf_rne(fB[4*q+2]), h3 = f2bf_rne(fB[4*q+3]);
                hi.x = h0; hi.y = h1; hi.z = h2; hi.w = h3;
                lo.x = f2bf_rne(fB[4*q+0] - bf2f(h0));
                lo.y = f2bf_rne(fB[4*q+1] - bf2f(h1));
                lo.z = f2bf_rne(fB[4*q+2] - bf2f(h2));
                lo.w = f2bf_rne(fB[4*q+3] - bf2f(h3));
                *(ushort4*)&Bh[buf][cB * BK + kgB + 4 * q] = hi;
                *(ushort4*)&Bl[buf][cB * BK + kgB + 4 * q] = lo;
            }
        }
    };

    if constexpr (PREB) issueB(0);
    loadRegs(0);
    writeLds(0);
    __syncthreads();

    const int NT = 3 * Kdim / BK;
    const int lo15 = lane & 15;
    const int hi4  = lane >> 4;
    const int koff = hi4 << 3;
    const int qs   = PREB ? (hi4 ^ ((lo15 >> 1) & 3)) : hi4;
    const int bOff = wc * 2048 + lo15 * 32 + qs * 8;

    for (int tile = 0; tile < NT; ++tile) {
        if (tile + 1 < NT) {
            if constexpr (PREB) issueB(tile + 1);
            loadRegs(tile + 1);
        }
        const int buf = tile & 1;
        bf16x8 ah[4], al[4], bh4[4], bl4[4];
        #pragma unroll
        for (int f = 0; f < 4; ++f) {
            int ar = wr * 64 + f * 16 + lo15;
            ah[f] = *(const bf16x8*)&Ah[ar][koff];
            al[f] = *(const bf16x8*)&Al[ar][koff];
            bh4[f] = *(const bf16x8*)&Bh[buf][f * 512 + bOff];
            bl4[f] = *(const bf16x8*)&Bl[buf][f * 512 + bOff];
        }
        #pragma unroll
        for (int i = 0; i < 4; ++i)
            #pragma unroll
            for (int j = 0; j < 4; ++j) {
                acc[i][j] = __builtin_amdgcn_mfma_f32_16x16x32_bf16(ah[i], bh4[j], acc[i][j], 0, 0, 0);
                acc[i][j] = __builtin_amdgcn_mfma_f32_16x16x32_bf16(ah[i], bl4[j], acc[i][j], 0, 0, 0);
                acc[i][j] = __builtin_amdgcn_mfma_f32_16x16x32_bf16(al[i], bh4[j], acc[i][j], 0, 0, 0);
            }

        if (tile + 1 < NT) {
            __syncthreads();
            writeLds(tile + 1);
            __syncthreads();
        }
    }

    epilogue(acc, rowBase, colBase, wr, wc, lo15, hi4,
             v, s, theta_s, g, g_fast, I_tonic, O, counter, wl, cap, out);
}

// ---------------- pass 2: fp64 fixup ----------------
__device__ __forceinline__ float ldw(const float* p, int c, int k, int tmode) {
    return tmode ? p[(size_t)c * Kdim + k] : p[(size_t)k * Ndim + c];
}

__global__ __launch_bounds__(256)
void nlif_fixup(const float* __restrict__ I_ext,
                const float* __restrict__ v,
                const float* __restrict__ g,
                const float* __restrict__ g_fast,
                const float* __restrict__ s,
                const float* __restrict__ theta_s,
                const float* __restrict__ w0,
                const float* __restrict__ w1,
                const float* __restrict__ w2,
                int tmode,
                const float* __restrict__ I_tonic,
                const float* __restrict__ O,
                const float* __restrict__ nt,
                const uint* __restrict__ counter,
                const uint* __restrict__ wl, int cap,
                float* __restrict__ out)
{
    uint cnt = *counter;
    int n = (int)(cnt < (uint)cap ? cnt : (uint)cap);
    int wgid = (int)((blockIdx.x * blockDim.x + threadIdx.x) >> 6);
    int lane = threadIdx.x & 63;
    int nw   = (int)((gridDim.x * blockDim.x) >> 6);
    const size_t SLAB = (size_t)Mdim * Ndim;

    for (int e = wgid; e < n; e += nw) {
        uint u = wl[e];
        int r = (int)(u >> 11), c = (int)(u & 2047);
        double acc = 0.0;
        for (int k = lane; k < Kdim; k += 64) {
            size_t ro = (size_t)r * Ndim + k;
            double wsyn = (double)ldw(w0, c, k, tmode) * (double)nt[k];
            acc += (double)g[ro] * wsyn;
            acc += (double)g_fast[ro] * (double)ldw(w1, c, k, tmode);
            acc += (double)I_ext[ro] * (double)ldw(w2, c, k, tmode);
        }
        #pragma unroll
        for (int m = 32; m; m >>= 1) acc += __shfl_xor(acc, m);

        if (lane == 0) {
            size_t off = (size_t)r * Ndim + c;
            double vv = (double)v[off], sv = (double)s[off], tv = (double)theta_s[off];
            double Itot   = acc + (double)I_tonic[c];
            double dvv    = (0.0 - vv + Itot) / 10.0;
            double v_next = vv + dvv;
            double gating = fmin(fmax(v_next, 0.0), 1.0);
            double dvc    = fmin(fmax(dvv, 0.0), 1.0);
            double s_new  = sv + (-sv + gating * dvc) / 10.0;
            bool   sp     = (v_next >= tv);
            out[off]            = (float)((double)O[c] * s_new);
            out[off + SLAB]     = (float)(sp ? (0.14 * vv - 0.12) : v_next);
            out[off + 2 * SLAB] = (float)(sp ? 1.0 : (-(double)g[off] / 10.0));
            out[off + 3 * SLAB] = (float)(sp ? 1.0 : -(double)g_fast[off]);
            out[off + 4 * SLAB] = (float)s_new;
            out[off + 5 * SLAB] = (float)(0.7 * tv + (sp ? 0.1 : 0.0));
        }
    }
}

// ---------------- helpers ----------------
__global__ void zero_cnt(uint* c) { *c = 0u; }

__global__ __launch_bounds__(256)
void transpose_k(const float* __restrict__ in, float* __restrict__ out) {
    __shared__ float tile[32][33];
    int bx = blockIdx.x * 32, by = blockIdx.y * 32;
    int tx = threadIdx.x & 31, ty = threadIdx.x >> 5;
    #pragma unroll
    for (int i = 0; i < 4; ++i)
        tile[ty + 8 * i][tx] = in[(size_t)(by + ty + 8 * i) * Ndim + bx + tx];
    __syncthreads();
    #pragma unroll
    for (int i = 0; i < 4; ++i)
        out[(size_t)(bx + ty + 8 * i) * Ndim + by + tx] = tile[tx][ty + 8 * i];
}

// ---------------- fallback: fp64 vector kernel (known-passing) ----------------
#define LDAF 132
#define LDBF 132
__global__ __launch_bounds__(256, 2)
void nlif_fp64(const float* __restrict__ I_ext, const float* __restrict__ v,
               const float* __restrict__ g, const float* __restrict__ g_fast,
               const float* __restrict__ s, const float* __restrict__ theta_s,
               const float* __restrict__ w, const float* __restrict__ W_fast,
               const float* __restrict__ W_in, const float* __restrict__ I_tonic,
               const float* __restrict__ O, const float* __restrict__ nt,
               float* __restrict__ out)
{
    __shared__ float As[BK][LDAF];
    __shared__ float Bs[BK][LDBF];
    const int t = threadIdx.x, tx = t & 15, ty = t >> 4;
    const int rowBase = blockIdx.y * BM, colBase = blockIdx.x * BN;
    const float* aSrc[3] = {g, g_fast, I_ext};
    const float* bSrc[3] = {w, W_fast, W_in};
    double acc[8][8];
    #pragma unroll
    for (int i = 0; i < 8; ++i)
        #pragma unroll
        for (int j = 0; j < 8; ++j) acc[i][j] = 0.0;
    float4 aReg[4], bReg[4];
    auto loadTile = [&](int tile) {
        const int sel = tile >> 6, kl = (tile & 63) << 5;
        const float* A = aSrc[sel]; const float* Bp = bSrc[sel];
        #pragma unroll
        for (int i = 0; i < 4; ++i) {
            int idx = t + 256 * i, r = idx >> 3, c4 = idx & 7;
            aReg[i] = *(const float4*)(A + (size_t)(rowBase + r) * Ndim + kl + c4 * 4);
        }
        #pragma unroll
        for (int i = 0; i < 4; ++i) {
            int idx = t + 256 * i, r = idx >> 5, c4 = idx & 31;
            float4 bv = *(const float4*)(Bp + (size_t)(kl + r) * Ndim + colBase + c4 * 4);
            if (sel == 0) { float sc = nt[kl + r]; bv.x *= sc; bv.y *= sc; bv.z *= sc; bv.w *= sc; }
            bReg[i] = bv;
        }
    };
    auto storeTile = [&]() {
        #pragma unroll
        for (int i = 0; i < 4; ++i) {
            int idx = t + 256 * i, r = idx >> 3, c = (idx & 7) * 4;
            As[c][r] = aReg[i].x; As[c + 1][r] = aReg[i].y;
            As[c + 2][r] = aReg[i].z; As[c + 3][r] = aReg[i].w;
        }
        #pragma unroll
        for (int i = 0; i < 4; ++i) {
            int idx = t + 256 * i, r = idx >> 5, c = (idx & 31) * 4;
            *(float4*)&Bs[r][c] = bReg[i];
        }
    };
    loadTile(0); storeTile(); __syncthreads();
    const int NT = 3 * Kdim / BK;
    for (int tile = 0; tile < NT; ++tile) {
        if (tile + 1 < NT) loadTile(tile + 1);
        #pragma unroll 8
        for (int k = 0; k < BK; ++k) {
            float4 a0 = *(const float4*)&As[k][ty * 4];
            float4 a1 = *(const float4*)&As[k][ty * 4 + 64];
            float4 b0 = *(const float4*)&Bs[k][tx * 4];
            float4 b1 = *(const float4*)&Bs[k][tx * 4 + 64];
            double ad[8] = {a0.x, a0.y, a0.z, a0.w, a1.x, a1.y, a1.z, a1.w};
            double bd[8] = {b0.x, b0.y, b0.z, b0.w, b1.x, b1.y, b1.z, b1.w};
            #pragma unroll
            for (int ri = 0; ri < 8; ++ri)
                #pragma unroll
                for (int cj = 0; cj < 8; ++cj)
                    acc[ri][cj] = fma(ad[ri], bd[cj], acc[ri][cj]);
        }
        if (tile + 1 < NT) { __syncthreads(); storeTile(); __syncthreads(); }
    }
    const size_t SLAB = (size_t)Mdim * Ndim;
    #pragma unroll
    for (int ri = 0; ri < 8; ++ri) {
        int row = rowBase + ty * 4 + (ri & 3) + ((ri >> 2) << 6);
        #pragma unroll
        for (int cg = 0; cg < 2; ++cg) {
            int col = colBase + tx * 4 + cg * 64;
            size_t off = (size_t)row * Ndim + col;
            #pragma unroll
            for (int e = 0; e < 4; ++e) {
                size_t o = off + e;
                double Itot   = acc[ri][cg * 4 + e] + (double)I_tonic[col + e];
                double vv = v[o], sv = s[o], tv = theta_s[o];
                double dvv    = (0.0 - vv + Itot) / 10.0;
                double v_next = vv + dvv;
                double gating = fmin(fmax(v_next, 0.0), 1.0);
                double dvc    = fmin(fmax(dvv, 0.0), 1.0);
                double s_new  = sv + (-sv + gating * dvc) / 10.0;
                bool   sp     = (v_next >= tv);
                out[o]            = (float)((double)O[col + e] * s_new);
                out[o + SLAB]     = (float)(sp ? (0.14 * vv - 0.12) : v_next);
                out[o + 2 * SLAB] = (float)(sp ? 1.0 : (-(double)g[o] / 10.0));
                out[o + 3 * SLAB] = (float)(sp ? 1.0 : -(double)g_fast[o]);
                out[o + 4 * SLAB] = (float)s_new;
                out[o + 5 * SLAB] = (float)(0.7 * tv + (sp ? 0.1 : 0.0));
            }
        }
    }
}

extern "C" void kernel_launch(void* const* d_in, const int* in_sizes, int n_in,
                              void* d_out, int out_size, void* d_ws, size_t ws_size,
                              hipStream_t stream) {
    const float* I_ext   = (const float*)d_in[0];
    const float* v       = (const float*)d_in[1];
    const float* g       = (const float*)d_in[2];
    const float* g_fast  = (const float*)d_in[3];
    const float* s       = (const float*)d_in[4];
    const float* theta_s = (const float*)d_in[5];
    const float* w       = (const float*)d_in[6];
    const float* W_fast  = (const float*)d_in[7];
    const float* W_in    = (const float*)d_in[8];
    const float* I_tonic = (const float*)d_in[9];
    const float* O       = (const float*)d_in[10];
    const float* nt      = (const float*)d_in[11];
    float* out           = (float*)d_out;

    const size_t WT_B  = 3 * PLE * sizeof(float);    // 50.3 MB
    const size_t BPL_B = 6 * PLE * sizeof(ushort);   // 50.3 MB
    const size_t APL_B = 6 * APLE * sizeof(ushort);  // 100.7 MB
    const size_t WL_B  = (size_t)1 << 22;            // 4 MB

    uint8_t* ws = (uint8_t*)d_ws;
    dim3 grid(Ndim / BN, Mdim / BM);                 // 512 blocks

    if (ws_size < (1u << 20) + 256) {
        nlif_fp64<<<grid, 256, 0, stream>>>(I_ext, v, g, g_fast, s, theta_s,
                                            w, W_fast, W_in, I_tonic, O, nt, out);
        return;
    }

    uint* counter = (uint*)ws;
    zero_cnt<<<1, 1, 0, stream>>>(counter);

    if (ws_size >= 256 + WT_B + BPL_B + APL_B + WL_B) {
        // ---- FULL2 tier: A+B DMA ----
        float*  wT  = (float*)(ws + 256);
        ushort* bpl = (ushort*)(ws + 256 + WT_B);
        ushort* apl = (ushort*)(ws + 256 + WT_B + BPL_B);
        uint*   wl  = (uint*)(ws + 256 + WT_B + BPL_B + APL_B);
        int cap = (int)(WL_B / 4);

        dim3 pg(Ndim / 32, Kdim / 32, 3);
        nlif_prep<<<pg, 256, 0, stream>>>(w, W_fast, W_in, nt, wT, bpl);
        nlif_prep2<<<3 * 4096, 256, 0, stream>>>(g, g_fast, I_ext, apl);
        nlif_pass1_dma<<<grid, 256, 0, stream>>>(v, g, g_fast, s, theta_s,
                                                 apl, bpl, I_tonic, O,
                                                 counter, wl, cap, out);
        nlif_fixup<<<256, 256, 0, stream>>>(I_ext, v, g, g_fast, s, theta_s,
                                            wT, wT + PLE, wT + 2 * PLE, 1,
                                            I_tonic, O, nt, counter, wl, cap, out);
    } else if (ws_size >= 256 + WT_B + BPL_B + WL_B) {
        // ---- FULL tier (round-8) ----
        float*  wT  = (float*)(ws + 256);
        ushort* bpl = (ushort*)(ws + 256 + WT_B);
        uint*   wl  = (uint*)(ws + 256 + WT_B + BPL_B);
        int cap = (int)(WL_B / 4);

        dim3 pg(Ndim / 32, Kdim / 32, 3);
        nlif_prep<<<pg, 256, 0, stream>>>(w, W_fast, W_in, nt, wT, bpl);
        nlif_pass1<1><<<grid, 256, 0, stream>>>(I_ext, v, g, g_fast, s, theta_s,
                                                w, W_fast, W_in, bpl,
                                                I_tonic, O, nt, counter, wl, cap, out);
        nlif_fixup<<<256, 256, 0, stream>>>(I_ext, v, g, g_fast, s, theta_s,
                                            wT, wT + PLE, wT + 2 * PLE, 1,
                                            I_tonic, O, nt, counter, wl, cap, out);
    } else if (ws_size >= 256 + WT_B + (1u << 20)) {
        // ---- MID tier ----
        float* wT = (float*)(ws + 256);
        uint*  wl = (uint*)(ws + 256 + WT_B);
        size_t cap = (ws_size - 256 - WT_B) / 4;
        if (cap > (1u << 20)) cap = (1u << 20);

        dim3 tg(Ndim / 32, Kdim / 32);
        transpose_k<<<tg, 256, 0, stream>>>(w, wT);
        transpose_k<<<tg, 256, 0, stream>>>(W_fast, wT + PLE);
        transpose_k<<<tg, 256, 0, stream>>>(W_in, wT + 2 * PLE);
        nlif_pass1<0><<<grid, 256, 0, stream>>>(I_ext, v, g, g_fast, s, theta_s,
                                                w, W_fast, W_in, nullptr,
                                                I_tonic, O, nt, counter, wl, (int)cap, out);
        nlif_fixup<<<256, 256, 0, stream>>>(I_ext, v, g, g_fast, s, theta_s,
                                            wT, wT + PLE, wT + 2 * PLE, 1,
                                            I_tonic, O, nt, counter, wl, (int)cap, out);
    } else {
        // ---- LOW tier ----
        uint* wl = (uint*)(ws + 256);
        size_t cap = (ws_size - 256) / 4;
        if (cap > (1u << 20)) cap = (1u << 20);
        nlif_pass1<0><<<grid, 256, 0, stream>>>(I_ext, v, g, g_fast, s, theta_s,
                                                w, W_fast, W_in, nullptr,
                                                I_tonic, O, nt, counter, wl, (int)cap, out);
        nlif_fixup<<<256, 256, 0, stream>>>(I_ext, v, g, g_fast, s, theta_s,
                                            w, W_fast, W_in, 0,
                                            I_tonic, O, nt, counter, wl, (int)cap, out);
    }
}